// Round 8
// baseline (392.606 us; speedup 1.0000x reference)
//
#include <hip/hip_runtime.h>
#include <math.h>

// ---------------------------------------------------------------------------
// TemporalFlowCell forward, MI355X.  Round 11: BARRIER-FREE 1-wave GEMMs.
//   Rounds 2-10 post-mortem: seven schedule variants all pin gemm1 at ~80 µs
//   with Occupancy ~20% even when 4+ blocks/CU fit -> 4-wave barrier
//   lockstep prevents wave staggering (m114 TLP needs independent phases).
//   gemm1 -> 64-thread (1-wave) blocks, 32x64 tile, grid 4096 (16 blk/CU),
//   3-buf 4 KB A-stage, counted vmcnt(4) private to the wave, NO barriers.
//   gemm2 -> same: 64x64 tile, grid 8192, BK=32, B direct from L2.
//   B operands (WinT/WcT, 512 KB, L2-resident) direct to registers.
//   XCD-chunked bijective block swizzles keep A panels L2-hot.
// Pipeline: beta = x @ W_in^T; per-chunk 128-step local scan fp32 (chunks
// decouple: lam^128 ~ 2e-34); carries[c] = couple(last[c-1]); fixup adds
// Re(lam^{t+1} carry) closed-form parallel over t; out = rez @ Wcomb^T.
// LDS staging via global_load_lds width=16, XOR granule swizzle on the GLOBAL
// address side (LDS dest is wave-uniform base + lane*16 — m104).
// W_in bf16 copy parked in d_out (free scratch until GEMM2 overwrites).
// ---------------------------------------------------------------------------

typedef __attribute__((ext_vector_type(8))) short short8;
typedef __attribute__((ext_vector_type(4))) float f32x4;

#define EPS_RES 0.01f

union U8 { unsigned u[4]; short8 s8; };

// round-half-up bf16: same half-ULP error bound as RNE (ties go up)
__device__ __forceinline__ unsigned short f2bf(float f) {
  unsigned u = __float_as_uint(f) + 0x8000u;
  return (unsigned short)(u >> 16);
}
__device__ __forceinline__ float bf2f(unsigned short h) {
  return __uint_as_float(((unsigned)h) << 16);
}
// pack bf16(f1)<<16 | bf16(f0) in 3 VALU ops (2 adds + v_perm)
__device__ __forceinline__ unsigned pk2bf(float f0, float f1) {
  return __builtin_amdgcn_perm(__float_as_uint(f1) + 0x8000u,
                               __float_as_uint(f0) + 0x8000u, 0x07060302u);
}
__device__ __forceinline__ void gl_lds16(const void* g, void* l) {
  __builtin_amdgcn_global_load_lds(
      (const __attribute__((address_space(1))) unsigned*)g,
      (__attribute__((address_space(3))) unsigned*)l, 16, 0, 0);
}

// ---------------- setup: norm partials (blocks 0-63) + W_in->bf16 ----------
__global__ __launch_bounds__(256) void k_setup(const float* __restrict__ M,
                                               float* __restrict__ part,
                                               const float* __restrict__ W,
                                               unsigned short* __restrict__ o) {
  const int bid = blockIdx.x;
  if (bid < 64) {
    const int i = (bid * 256 + threadIdx.x) * 4;
    const float4 v = *(const float4*)(M + i);
    float s = v.x * v.x + v.y * v.y + v.z * v.z + v.w * v.w;
    #pragma unroll
    for (int off = 32; off > 0; off >>= 1) s += __shfl_down(s, off);
    __shared__ float red[4];
    const int lane = threadIdx.x & 63, wv = threadIdx.x >> 6;
    if (lane == 0) red[wv] = s;
    __syncthreads();
    if (threadIdx.x == 0)
      part[bid] = red[0] + red[1] + red[2] + red[3];
  } else {
    const int i = ((bid - 64) * 256 + threadIdx.x) * 4;
    float4 v = *(const float4*)(W + i);
    uint2 p;
    p.x = pk2bf(v.x, v.y);
    p.y = pk2bf(v.z, v.w);
    *(uint2*)(o + i) = p;
  }
}

// uniform inline reduction of the 64 norm partials (same order everywhere)
__device__ __forceinline__ float norm_scale(const float* __restrict__ part) {
  float nsum = 0.f;
  #pragma unroll
  for (int i = 0; i < 64; ++i) nsum += part[i];
  return EPS_RES / (sqrtf(nsum) + 1e-8f);
}

// ---------------- Wcomb^T[d][k] = W_out[d][k] + s*sum_j M[k][j]W_out[d][j] --
__global__ __launch_bounds__(256) void k_wcomb(const float* __restrict__ Wout,
                                               const float* __restrict__ Mm,
                                               const float* __restrict__ npart,
                                               unsigned short* __restrict__ WcT) {
  const int d0 = blockIdx.x * 8;
  const int k = threadIdx.x;
  __shared__ float wl[8][256];
  #pragma unroll
  for (int dd = 0; dd < 8; ++dd) wl[dd][k] = Wout[(size_t)(d0 + dd) * 256 + k];
  __syncthreads();
  float acc[8] = {0.f, 0.f, 0.f, 0.f, 0.f, 0.f, 0.f, 0.f};
  const float4* Mr = (const float4*)(Mm + (size_t)k * 256);
  for (int j4 = 0; j4 < 64; ++j4) {
    const float4 m4 = Mr[j4];
    #pragma unroll
    for (int dd = 0; dd < 8; ++dd) {
      acc[dd] = fmaf(m4.x, wl[dd][j4 * 4 + 0], acc[dd]);
      acc[dd] = fmaf(m4.y, wl[dd][j4 * 4 + 1], acc[dd]);
      acc[dd] = fmaf(m4.z, wl[dd][j4 * 4 + 2], acc[dd]);
      acc[dd] = fmaf(m4.w, wl[dd][j4 * 4 + 3], acc[dd]);
    }
  }
  const float s = norm_scale(npart);
  #pragma unroll
  for (int dd = 0; dd < 8; ++dd)
    WcT[(size_t)(d0 + dd) * 256 + k] =
        f2bf(Wout[(size_t)(d0 + dd) * 256 + k] + s * acc[dd]);
}

// ---------------- GEMM1: beta[32768,256] = x[32768,1024] @ W_in^T ----------
// 1-wave blocks, 32x64 tile, grid 4096. NO barriers: private counted vmcnt.
// A fp32 staged per step: 32 rows x 32 fp32 = 4 KB = 4 gl_lds16 (8 rows x
// 8 granules of 16B each), swizzle g^(row&7). 3 buffers, 2 tiles in flight;
// vmcnt(4) = all but the newest stage retired (in-order vmcnt, m135).
// B (WinT, 512 KB L2-resident) DIRECT to registers as k-contiguous short8.
__global__ __launch_bounds__(64) void k_gemm1(const float* __restrict__ A,
                                              const unsigned short* __restrict__ Bw,
                                              float* __restrict__ C) {
  __shared__ __align__(16) float lA[3][32 * 32];   // 3 x 4 KB
  const int lane = threadIdx.x;
  // XCD-chunked bijective swizzle (4096 = 8 x 512): 512 consecutive logical
  // tiles per XCD; 4 n-tiles of an m-panel are consecutive -> x panel L2-hot.
  const int wg = ((blockIdx.x & 7) << 9) + (blockIdx.x >> 3);
  const int m0 = (wg >> 2) * 32;           // 1024 m-tiles
  const int n0 = (wg & 3) * 64;            // 4 n-tiles
  const int lrow = lane & 15, q = lane >> 4;

  // staging lane->global map: instr j covers rows j*8..j*8+7
  const int s_r8 = lane >> 3;              // row within 8-row group (0..7)
  const int s_g = (lane & 7) ^ s_r8;       // logical granule (swizzled)

  // B fragment bases (row = n index, k-contiguous per lane)
  const unsigned short* Bt[4];
  #pragma unroll
  for (int t = 0; t < 4; ++t)
    Bt[t] = Bw + (size_t)(n0 + t * 16 + lrow) * 1024 + q * 8;

  f32x4 acc[2][4] = {};

  auto stage = [&](int bf, int k0) {
    #pragma unroll
    for (int j = 0; j < 4; ++j)
      gl_lds16(A + (size_t)(m0 + j * 8 + s_r8) * 1024 + k0 + s_g * 4,
               &lA[bf][(j * 8) * 32]);
  };

  auto compute = [&](int cur, int s) {
    short8 bfv[4];
    #pragma unroll
    for (int tn = 0; tn < 4; ++tn)
      bfv[tn] = *(const short8*)(Bt[tn] + s * 32);
    short8 af[2];
    #pragma unroll
    for (int tm = 0; tm < 2; ++tm) {
      const int ra = tm * 16 + lrow, sw = ra & 7;
      const float4 lo = *(const float4*)&lA[cur][ra * 32 + (((2 * q) ^ sw) << 2)];
      const float4 hi = *(const float4*)&lA[cur][ra * 32 + (((2 * q + 1) ^ sw) << 2)];
      U8 u;
      u.u[0] = pk2bf(lo.x, lo.y);
      u.u[1] = pk2bf(lo.z, lo.w);
      u.u[2] = pk2bf(hi.x, hi.y);
      u.u[3] = pk2bf(hi.z, hi.w);
      af[tm] = u.s8;
    }
    #pragma unroll
    for (int tm = 0; tm < 2; ++tm)
      #pragma unroll
      for (int tn = 0; tn < 4; ++tn)
        acc[tm][tn] = __builtin_amdgcn_mfma_f32_16x16x32_bf16(
            af[tm], bfv[tn], acc[tm][tn], 0, 0, 0);
  };

  stage(0, 0);
  stage(1, 32);
  for (int s = 0; s < 31; ++s) {
    // newest 4 outstanding = stage(s+1); everything older (stage s) retired
    asm volatile("s_waitcnt vmcnt(4)" ::: "memory");
    if (s + 2 < 32) stage((s + 2) % 3, (s + 2) * 32);  // issue-early (T14)
    compute(s % 3, s);
  }
  asm volatile("s_waitcnt vmcnt(0)" ::: "memory");
  compute(31 % 3, 31);

  // C/D layout: col = lane&15, row = (lane>>4)*4 + reg   [verified m89/m91]
  #pragma unroll
  for (int tm = 0; tm < 2; ++tm)
    #pragma unroll
    for (int tn = 0; tn < 4; ++tn)
      #pragma unroll
      for (int r = 0; r < 4; ++r)
        C[(size_t)(m0 + tm * 16 + q * 4 + r) * 256 + (n0 + tn * 16 + lrow)] =
            acc[tm][tn][r];
}

// ---------------- GEMM2: out[32768,1024] = rez[32768,256] @ WcT^T ----------
// 1-wave blocks, 64x64 tile, grid 8192, BK=32, NO barriers. A (rez bf16)
// staged: 64 rows x 32 bf16 = 4 KB = 4 gl_lds16 (16 rows x 4 granules),
// swizzle g^((row>>1)&3) (round-5 proven path). 3 buffers, vmcnt(4).
// B (WcT, 512 KB L2-resident) DIRECT. XCD-chunked swizzle (8192 = 8x1024):
// 16 n-tiles of an m-panel consecutive on one XCD -> rez panel L2-hot.
__global__ __launch_bounds__(64) void k_gemm2(const unsigned short* __restrict__ A,
                                              const unsigned short* __restrict__ Bw,
                                              float* __restrict__ C) {
  __shared__ __align__(16) unsigned short lA[3][64 * 32];  // 3 x 4 KB
  const int lane = threadIdx.x;
  const int wg = ((blockIdx.x & 7) << 10) + (blockIdx.x >> 3);
  const int m0 = (wg >> 4) * 64;           // 512 m-tiles
  const int n0 = (wg & 15) * 64;           // 16 n-tiles
  const int lrow = lane & 15, q = lane >> 4;

  // staging lane->global map: instr j covers rows j*16..j*16+15
  const int s_r16 = lane >> 2;                       // row in group (0..15)
  const int s_g = (lane & 3) ^ ((s_r16 >> 1) & 3);   // logical granule

  const unsigned short* Bt[4];
  #pragma unroll
  for (int t = 0; t < 4; ++t)
    Bt[t] = Bw + (size_t)(n0 + t * 16 + lrow) * 256 + q * 8;

  f32x4 acc[4][4] = {};

  auto stage = [&](int bf, int k0) {
    #pragma unroll
    for (int j = 0; j < 4; ++j)
      gl_lds16(A + (size_t)(m0 + j * 16 + s_r16) * 256 + k0 + s_g * 8,
               &lA[bf][(j * 16) * 32]);
  };

  auto compute = [&](int cur, int s) {
    short8 af[4], bfv[4];
    #pragma unroll
    for (int t = 0; t < 4; ++t) {
      bfv[t] = *(const short8*)(Bt[t] + s * 32);
      const int ra = t * 16 + lrow;
      af[t] = *(const short8*)&lA[cur][ra * 32 + ((q ^ ((ra >> 1) & 3)) << 3)];
    }
    #pragma unroll
    for (int tm = 0; tm < 4; ++tm)
      #pragma unroll
      for (int tn = 0; tn < 4; ++tn)
        acc[tm][tn] = __builtin_amdgcn_mfma_f32_16x16x32_bf16(
            af[tm], bfv[tn], acc[tm][tn], 0, 0, 0);
  };

  stage(0, 0);
  stage(1, 32);
  for (int s = 0; s < 7; ++s) {
    asm volatile("s_waitcnt vmcnt(4)" ::: "memory");
    if (s + 2 < 8) stage((s + 2) % 3, (s + 2) * 32);
    compute(s % 3, s);
  }
  asm volatile("s_waitcnt vmcnt(0)" ::: "memory");
  compute(7 % 3, 7);

  #pragma unroll
  for (int tm = 0; tm < 4; ++tm)
    #pragma unroll
    for (int tn = 0; tn < 4; ++tn)
      #pragma unroll
      for (int r = 0; r < 4; ++r)
        C[(size_t)(m0 + tm * 16 + q * 4 + r) * 1024 + (n0 + tn * 16 + lrow)] =
            acc[tm][tn][r];
}

// ---------------- local scan per (chunk, batch): 256 k-lanes ----------------
__global__ __launch_bounds__(256) void k_scan(const float* __restrict__ beta,
                                              unsigned short* __restrict__ rez,
                                              float* __restrict__ lastR,
                                              float* __restrict__ lastI,
                                              const float* __restrict__ alpha_raw,
                                              const float* __restrict__ omega) {
  const int c = blockIdx.x & 31, b = blockIdx.x >> 5;
  const int k = threadIdx.x;
  const float a = alpha_raw[k];
  const float sig = 1.f / (1.f + expf(-a));
  const float mag = 0.1f + sig * (0.99f - 0.1f);
  const float om = omega[k] * 0.1f;
  const float lc = mag * cosf(om), ls = mag * sinf(om);

  const size_t m0 = (size_t)b * 4096 + (size_t)c * 128;
  const float* bp = beta + m0 * 256 + k;
  unsigned short* rp = rez + m0 * 256 + k;
  float r = 0.f, im = 0.f;
  #pragma unroll 8
  for (int t = 0; t < 128; ++t) {
    float be = bp[(size_t)t * 256];
    float nr = fmaf(lc, r, fmaf(-ls, im, be));
    float ni = fmaf(ls, r, lc * im);
    r = nr; im = ni;
    rp[(size_t)t * 256] = f2bf(r);
  }
  const int idx = (c * 8 + b) * 256 + k;
  lastR[idx] = r;
  lastI[idx] = im;
}

// ---------------- carries[c] = couple(last[c-1]); couple(v)=v + s*(v@M) -----
__global__ __launch_bounds__(256) void k_carry(const float* __restrict__ lastR,
                                               const float* __restrict__ lastI,
                                               const float* __restrict__ Mm,
                                               const float* __restrict__ npart,
                                               float* __restrict__ carR,
                                               float* __restrict__ carI) {
  const int c = blockIdx.x & 31, b = blockIdx.x >> 5;
  const int j = threadIdx.x;
  const int oidx = (c * 8 + b) * 256 + j;
  if (c == 0) {  // uniform over block: no barrier divergence
    carR[oidx] = 0.f;
    carI[oidx] = 0.f;
    return;
  }
  __shared__ float lr[256], li[256];
  const int iidx = ((c - 1) * 8 + b) * 256;
  lr[j] = lastR[iidx + j];
  li[j] = lastI[iidx + j];
  __syncthreads();
  float ar = 0.f, ai = 0.f;
  for (int kk = 0; kk < 256; ++kk) {
    float m = Mm[(size_t)kk * 256 + j];
    ar = fmaf(lr[kk], m, ar);
    ai = fmaf(li[kk], m, ai);
  }
  const float s = norm_scale(npart);
  carR[oidx] = lr[j] + s * ar;
  carI[oidx] = li[j] + s * ai;
}

// ---------------- fixup: rez[c,b,t,k] += Re(lam^{t+1} * carry), t<64 --------
// Closed form per t (no serial chain): lam^{t+1} = mag^{t+1} e^{i(t+1)om}.
// mag <= 0.545 => lam^{t+1}*carry < 1e-17 beyond t=64; lam^128 ~ 2e-34 (drop).
// Grid: 31 chunks x 8 batch x 8 t-groups = 1984 blocks, 8 t per thread.
__global__ __launch_bounds__(256) void k_fixup(unsigned short* __restrict__ rez,
                                               const float* __restrict__ carR,
                                               const float* __restrict__ carI,
                                               const float* __restrict__ alpha_raw,
                                               const float* __restrict__ omega) {
  const int tg = blockIdx.x & 7;
  const int cb = blockIdx.x >> 3;           // 0..247
  const int b = cb & 7, c = (cb >> 3) + 1;  // c in [1,32)
  const int k = threadIdx.x;
  const float a = alpha_raw[k];
  const float sig = 1.f / (1.f + expf(-a));
  const float mag = 0.1f + sig * (0.99f - 0.1f);
  const float om = omega[k] * 0.1f;
  const float l2m = log2f(mag);

  const float cr = carR[(c * 8 + b) * 256 + k];
  const float ci = carI[(c * 8 + b) * 256 + k];
  unsigned short* rp =
      rez + ((size_t)b * 4096 + (size_t)c * 128 + tg * 8) * 256 + k;
  #pragma unroll
  for (int tt = 0; tt < 8; ++tt) {
    const float tp1 = (float)(tg * 8 + tt + 1);
    const float p = exp2f(tp1 * l2m);           // mag^(t+1)
    const float ang = tp1 * om;
    const float hr = p * (cosf(ang) * cr - sinf(ang) * ci);
    rp[(size_t)tt * 256] = f2bf(bf2f(rp[(size_t)tt * 256]) + hr);
  }
}

// ---------------------------------------------------------------------------
extern "C" void kernel_launch(void* const* d_in, const int* in_sizes, int n_in,
                              void* d_out, int out_size, void* d_ws,
                              size_t ws_size, hipStream_t stream) {
  const float* x         = (const float*)d_in[0];  // (8,4096,1024)
  const float* alpha_raw = (const float*)d_in[1];  // (256,)
  const float* omega     = (const float*)d_in[2];  // (256,)
  const float* W_in      = (const float*)d_in[3];  // (256,1024)
  const float* W_out     = (const float*)d_in[4];  // (1024,256)
  const float* Mm        = (const float*)d_in[5];  // (256,256)
  float* out = (float*)d_out;                      // (8,4096,1024) fp32

  char* ws = (char*)d_ws;
  float*          beta  = (float*)(ws);                         // 33,554,432 B
  unsigned short* rez   = (unsigned short*)(ws + 33554432);     // 16,777,216 B
  float*          lastR = (float*)(ws + 50331648);              //    262,144 B
  float*          lastI = (float*)(ws + 50331648 + 262144);
  float*          carR  = (float*)(ws + 50331648 + 2 * 262144);
  float*          carI  = (float*)(ws + 50331648 + 3 * 262144);
  unsigned short* WcT   = (unsigned short*)(ws + 50331648 + 4 * 262144); // 524,288 B
  float*          npart = (float*)(ws + 50331648 + 4 * 262144 + 524288); // 256 B
  // W_in bf16 copy parked in d_out (free scratch until GEMM2 overwrites it)
  unsigned short* WinT  = (unsigned short*)d_out;               //    524,288 B

  k_setup<<<320, 256, 0, stream>>>(Mm, npart, W_in, WinT);
  k_wcomb<<<128, 256, 0, stream>>>(W_out, Mm, npart, WcT);
  k_gemm1<<<4096, 64, 0, stream>>>(x, WinT, beta);
  k_scan<<<256, 256, 0, stream>>>(beta, rez, lastR, lastI, alpha_raw, omega);
  k_carry<<<256, 256, 0, stream>>>(lastR, lastI, Mm, npart, carR, carI);
  k_fixup<<<1984, 256, 0, stream>>>(rez, carR, carI, alpha_raw, omega);
  k_gemm2<<<8192, 64, 0, stream>>>(rez, WcT, out);
}

// Round 9
// 320.008 us; speedup vs baseline: 1.2269x; 1.2269x over previous
//
#include <hip/hip_runtime.h>
#include <math.h>

// ---------------------------------------------------------------------------
// TemporalFlowCell forward, MI355X.  Round 12 (base = round 5's 329.7 µs):
//   GEMM1 + scan FUSED: BM=128 = one chunk, so the 128-step recurrence is
//   block-local. After the K-loop the fp32 acc tile is parked in the freed
//   72 KB staging arena ([128][132] padded), 128 threads scan their own k
//   column (bitwise-identical op order to the old k_scan), write rez bf16 +
//   lastR/lastI. Kills beta (67 MB HBM round-trip), one launch, and the
//   scan kernel's 1-block/CU latency exposure.
//   GEMM1 K-loop: round-3 128x128 geometry + round-5 counted-vmcnt 3-buf
//   (6 loads/lane/tile, 2 tiles in flight, vmcnt(6), raw s_barrier).
//   GEMM2, setup, wcomb, carry, fixup: verbatim round 5 (best observed).
// Pipeline: rez = scan(x @ W_in^T); carries[c] = couple(last[c-1]); fixup
// adds Re(lam^{t+1} carry) closed-form parallel over t; out = rez @ Wcomb^T.
// LDS staging via global_load_lds width=16, XOR granule swizzle on the GLOBAL
// address side (LDS dest is wave-uniform base + lane*16 — m104).
// W_in bf16 copy parked in d_out (free scratch until GEMM2 overwrites).
// ---------------------------------------------------------------------------

typedef __attribute__((ext_vector_type(8))) short short8;
typedef __attribute__((ext_vector_type(4))) float f32x4;

#define EPS_RES 0.01f

union U8 { unsigned u[4]; short8 s8; };

// round-half-up bf16: same half-ULP error bound as RNE (ties go up)
__device__ __forceinline__ unsigned short f2bf(float f) {
  unsigned u = __float_as_uint(f) + 0x8000u;
  return (unsigned short)(u >> 16);
}
__device__ __forceinline__ float bf2f(unsigned short h) {
  return __uint_as_float(((unsigned)h) << 16);
}
// pack bf16(f1)<<16 | bf16(f0) in 3 VALU ops (2 adds + v_perm)
__device__ __forceinline__ unsigned pk2bf(float f0, float f1) {
  return __builtin_amdgcn_perm(__float_as_uint(f1) + 0x8000u,
                               __float_as_uint(f0) + 0x8000u, 0x07060302u);
}
__device__ __forceinline__ void gl_lds16(const void* g, void* l) {
  __builtin_amdgcn_global_load_lds(
      (const __attribute__((address_space(1))) unsigned*)g,
      (__attribute__((address_space(3))) unsigned*)l, 16, 0, 0);
}

// ---------------- setup: norm partials (blocks 0-63) + W_in->bf16 ----------
__global__ __launch_bounds__(256) void k_setup(const float* __restrict__ M,
                                               float* __restrict__ part,
                                               const float* __restrict__ W,
                                               unsigned short* __restrict__ o) {
  const int bid = blockIdx.x;
  if (bid < 64) {
    const int i = (bid * 256 + threadIdx.x) * 4;
    const float4 v = *(const float4*)(M + i);
    float s = v.x * v.x + v.y * v.y + v.z * v.z + v.w * v.w;
    #pragma unroll
    for (int off = 32; off > 0; off >>= 1) s += __shfl_down(s, off);
    __shared__ float red[4];
    const int lane = threadIdx.x & 63, wv = threadIdx.x >> 6;
    if (lane == 0) red[wv] = s;
    __syncthreads();
    if (threadIdx.x == 0)
      part[bid] = red[0] + red[1] + red[2] + red[3];
  } else {
    const int i = ((bid - 64) * 256 + threadIdx.x) * 4;
    float4 v = *(const float4*)(W + i);
    uint2 p;
    p.x = pk2bf(v.x, v.y);
    p.y = pk2bf(v.z, v.w);
    *(uint2*)(o + i) = p;
  }
}

// uniform inline reduction of the 64 norm partials (same order everywhere)
__device__ __forceinline__ float norm_scale(const float* __restrict__ part) {
  float nsum = 0.f;
  #pragma unroll
  for (int i = 0; i < 64; ++i) nsum += part[i];
  return EPS_RES / (sqrtf(nsum) + 1e-8f);
}

// ---------------- Wcomb^T[d][k] = W_out[d][k] + s*sum_j M[k][j]W_out[d][j] --
__global__ __launch_bounds__(256) void k_wcomb(const float* __restrict__ Wout,
                                               const float* __restrict__ Mm,
                                               const float* __restrict__ npart,
                                               unsigned short* __restrict__ WcT) {
  const int d0 = blockIdx.x * 8;
  const int k = threadIdx.x;
  __shared__ float wl[8][256];
  #pragma unroll
  for (int dd = 0; dd < 8; ++dd) wl[dd][k] = Wout[(size_t)(d0 + dd) * 256 + k];
  __syncthreads();
  float acc[8] = {0.f, 0.f, 0.f, 0.f, 0.f, 0.f, 0.f, 0.f};
  const float4* Mr = (const float4*)(Mm + (size_t)k * 256);
  for (int j4 = 0; j4 < 64; ++j4) {
    const float4 m4 = Mr[j4];
    #pragma unroll
    for (int dd = 0; dd < 8; ++dd) {
      acc[dd] = fmaf(m4.x, wl[dd][j4 * 4 + 0], acc[dd]);
      acc[dd] = fmaf(m4.y, wl[dd][j4 * 4 + 1], acc[dd]);
      acc[dd] = fmaf(m4.z, wl[dd][j4 * 4 + 2], acc[dd]);
      acc[dd] = fmaf(m4.w, wl[dd][j4 * 4 + 3], acc[dd]);
    }
  }
  const float s = norm_scale(npart);
  #pragma unroll
  for (int dd = 0; dd < 8; ++dd)
    WcT[(size_t)(d0 + dd) * 256 + k] =
        f2bf(Wout[(size_t)(d0 + dd) * 256 + k] + s * acc[dd]);
}

// ---------------- GEMM1+scan: rez = scan(x @ W_in^T) -----------------------
// 128x128 tile (BM=128 = one chunk), grid 512 = m-tile*2 + n-half.
// K-loop: 3-buf counted vmcnt(6) (6 gl_lds16/lane/tile: A 4, B 2).
// A fp32 rows of 32 = 8x16B granules, swizzle g^(r&7);
// B bf16 rows of 32 = 4 granules, swizzle g^((r>>1)&3).
// Epilogue: acc -> arena [128][132] fp32, 128 threads scan columns (same op
// order as the old k_scan), write rez bf16 + lastR/lastI.
__global__ __launch_bounds__(256) void k_gemm1(const float* __restrict__ A,
                                               const unsigned short* __restrict__ Bw,
                                               unsigned short* __restrict__ rez,
                                               float* __restrict__ lastR,
                                               float* __restrict__ lastI,
                                               const float* __restrict__ alpha_raw,
                                               const float* __restrict__ omega) {
  __shared__ __align__(16) char arena[73728];  // 3x16KB lA + 3x8KB lB; reused
  const int tid = threadIdx.x;
  const int wv = tid >> 6, lane = tid & 63;
  const int mt = blockIdx.x >> 1;          // 0..255: b = mt>>5, c = mt&31
  const int n0 = (blockIdx.x & 1) * 128;
  const int m0 = mt * 128;
  const int wm = wv & 1, wn = wv >> 1;
  const int lrow = lane & 15, q = lane >> 4;

  // staging lane->global mapping (swizzle on global side; LDS = base+lane*16)
  const int a_r8 = lane >> 3;                       // row within 8-row group
  const int a_gl = (lane & 7) ^ a_r8;               // logical 16B granule
  const int b_r16 = lane >> 2;                      // row within 16-row group
  const int b_gl = (lane & 3) ^ ((b_r16 >> 1) & 3);

  const float* Ab = A + (size_t)(m0 + wv * 32 + a_r8) * 1024 + a_gl * 4;
  const unsigned short* Bb =
      Bw + (size_t)(n0 + wv * 32 + b_r16) * 1024 + b_gl * 8;

  f32x4 acc[4][4] = {};

  auto stage = [&](int bf, int k0) {
    float* la = (float*)(arena + bf * 16384);
    unsigned short* lb = (unsigned short*)(arena + 49152 + bf * 8192);
    #pragma unroll
    for (int j = 0; j < 4; ++j)   // A: wave stages rows [wv*32, wv*32+32)
      gl_lds16(Ab + (size_t)j * 8 * 1024 + k0, &la[(wv * 32 + j * 8) * 32]);
    #pragma unroll
    for (int j = 0; j < 2; ++j)   // B: wave stages rows [wv*32, wv*32+32)
      gl_lds16(Bb + (size_t)j * 16 * 1024 + k0, &lb[(wv * 32 + j * 16) * 32]);
  };

  auto compute = [&](int cur) {
    const float* la = (const float*)(arena + cur * 16384);
    const unsigned short* lb =
        (const unsigned short*)(arena + 49152 + cur * 8192);
    short8 af[4], bfv[4];
    #pragma unroll
    for (int t = 0; t < 4; ++t) {
      const int ra = wm * 64 + t * 16 + lrow, sw = ra & 7;
      const float4 lo = *(const float4*)&la[ra * 32 + (((2 * q) ^ sw) << 2)];
      const float4 hi = *(const float4*)&la[ra * 32 + (((2 * q + 1) ^ sw) << 2)];
      U8 u;
      u.u[0] = pk2bf(lo.x, lo.y);
      u.u[1] = pk2bf(lo.z, lo.w);
      u.u[2] = pk2bf(hi.x, hi.y);
      u.u[3] = pk2bf(hi.z, hi.w);
      af[t] = u.s8;
      const int rb = wn * 64 + t * 16 + lrow;
      bfv[t] = *(const short8*)&lb[rb * 32 + (q ^ ((rb >> 1) & 3)) * 8];
    }
    #pragma unroll
    for (int tm = 0; tm < 4; ++tm)
      #pragma unroll
      for (int tn = 0; tn < 4; ++tn)
        acc[tm][tn] = __builtin_amdgcn_mfma_f32_16x16x32_bf16(
            af[tm], bfv[tn], acc[tm][tn], 0, 0, 0);
  };

  stage(0, 0);
  stage(1, 32);
  for (int j = 0; j < 31; ++j) {
    // my tile-j 6 loads retired; tile j+1's 6 stay in flight. Never 0.
    asm volatile("s_waitcnt vmcnt(6)" ::: "memory");
    __builtin_amdgcn_s_barrier();   // all waves' tile-j loads landed; all
                                    // waves done reading buf (j-1)%3
    if (j + 2 < 32) stage((j + 2) % 3, (j + 2) * 32);  // overwrites j-1: safe
    compute(j % 3);
  }
  asm volatile("s_waitcnt vmcnt(0)" ::: "memory");
  __builtin_amdgcn_s_barrier();
  compute(31 % 3);

  // ---- epilogue: fused scan (acc tile -> arena -> recurrence -> rez) ----
  __syncthreads();                  // all waves done reading staging bufs
  float* accL = (float*)arena;      // [128][132] fp32 = 67584 B
  const int colb = wn * 64 + lrow;
  #pragma unroll
  for (int tm = 0; tm < 4; ++tm)
    #pragma unroll
    for (int tn = 0; tn < 4; ++tn)
      #pragma unroll
      for (int r = 0; r < 4; ++r)
        accL[(wm * 64 + tm * 16 + q * 4 + r) * 132 + colb + tn * 16] =
            acc[tm][tn][r];
  __syncthreads();

  if (tid < 128) {
    const int k = n0 + tid;
    const float a = alpha_raw[k];
    const float sig = 1.f / (1.f + expf(-a));
    const float mag = 0.1f + sig * (0.99f - 0.1f);
    const float om = omega[k] * 0.1f;
    const float lc = mag * cosf(om), ls = mag * sinf(om);

    unsigned short* rp = rez + (size_t)m0 * 256 + k;
    float r = 0.f, im = 0.f;
    #pragma unroll 8
    for (int t = 0; t < 128; ++t) {
      float be = accL[t * 132 + tid];
      float nr = fmaf(lc, r, fmaf(-ls, im, be));
      float ni = fmaf(ls, r, lc * im);
      r = nr; im = ni;
      rp[(size_t)t * 256] = f2bf(r);
    }
    const int c = mt & 31, b = mt >> 5;
    const int idx = (c * 8 + b) * 256 + k;
    lastR[idx] = r;
    lastI[idx] = im;
  }
}

// ---------------- GEMM2: out[32768,1024] = rez[32768,256] @ WcT^T ----------
// 128x128 tile, BK=32, 3x16 KB LDS (3 blocks/CU). Counted-vmcnt pipeline;
// per tile each lane issues 4 gl_lds16 -> s_waitcnt vmcnt(4).
// Rows of 32 bf16 = 64B = 4 granules, swizzle g^((r>>1)&3).
// XCD-aware bijective swizzle: 8 N-tiles of one M-tile on one XCD.
__global__ __launch_bounds__(256) void k_gemm2(const unsigned short* __restrict__ A,
                                               const unsigned short* __restrict__ Bw,
                                               float* __restrict__ C) {
  __shared__ __align__(16) unsigned short lA[3][128 * 32];  // 3 x 8 KB
  __shared__ __align__(16) unsigned short lB[3][128 * 32];  // 3 x 8 KB
  const int tid = threadIdx.x;
  const int wv = tid >> 6, lane = tid & 63;
  const int bid = blockIdx.x + (blockIdx.y << 8);  // 0..2047
  const int xcd = bid & 7, ii = bid >> 3;          // ii: 0..255
  const int m0 = ((xcd << 5) + (ii >> 3)) * 128;   // 32 m-tiles per XCD
  const int n0 = (ii & 7) * 128;
  const int wm = wv & 1, wn = wv >> 1;
  const int lrow = lane & 15, q = lane >> 4;

  const int r16 = lane >> 2;                       // row within 16-row group
  const int g4 = (lane & 3) ^ ((r16 >> 1) & 3);    // logical 16B granule

  const unsigned short* Ab = A + (size_t)(m0 + wv * 32 + r16) * 256 + g4 * 8;
  const unsigned short* Bb = Bw + (size_t)(n0 + wv * 32 + r16) * 256 + g4 * 8;

  f32x4 acc[4][4] = {};

  auto stage = [&](int bf, int k0) {
    #pragma unroll
    for (int j = 0; j < 2; ++j) {  // wave stages rows [wv*32, wv*32+32)
      gl_lds16(Ab + (size_t)j * 16 * 256 + k0,
               &lA[bf][(wv * 32 + j * 16) * 32]);
      gl_lds16(Bb + (size_t)j * 16 * 256 + k0,
               &lB[bf][(wv * 32 + j * 16) * 32]);
    }
  };

  auto compute = [&](int cur) {
    short8 af[4], bfv[4];
    #pragma unroll
    for (int t = 0; t < 4; ++t) {
      const int ra = wm * 64 + t * 16 + lrow;
      af[t] = *(const short8*)&lA[cur][ra * 32 + ((q ^ ((ra >> 1) & 3)) << 3)];
      const int rb = wn * 64 + t * 16 + lrow;
      bfv[t] = *(const short8*)&lB[cur][rb * 32 + ((q ^ ((rb >> 1) & 3)) << 3)];
    }
    #pragma unroll
    for (int tm = 0; tm < 4; ++tm)
      #pragma unroll
      for (int tn = 0; tn < 4; ++tn)
        acc[tm][tn] = __builtin_amdgcn_mfma_f32_16x16x32_bf16(
            af[tm], bfv[tn], acc[tm][tn], 0, 0, 0);
  };

  stage(0, 0);
  stage(1, 32);
  for (int j = 0; j < 7; ++j) {
    asm volatile("s_waitcnt vmcnt(4)" ::: "memory");
    __builtin_amdgcn_s_barrier();
    if (j + 2 < 8) stage((j + 2) % 3, (j + 2) * 32);
    compute(j % 3);
  }
  asm volatile("s_waitcnt vmcnt(0)" ::: "memory");
  __builtin_amdgcn_s_barrier();
  compute(7 % 3);

  const int rbase = m0 + wm * 64 + (lane >> 4) * 4;
  const int cbase = n0 + wn * 64 + (lane & 15);
  #pragma unroll
  for (int tm = 0; tm < 4; ++tm)
    #pragma unroll
    for (int tn = 0; tn < 4; ++tn)
      #pragma unroll
      for (int r = 0; r < 4; ++r)
        C[(size_t)(rbase + tm * 16 + r) * 1024 + (cbase + tn * 16)] =
            acc[tm][tn][r];
}

// ---------------- carries[c] = couple(last[c-1]); couple(v)=v + s*(v@M) -----
__global__ __launch_bounds__(256) void k_carry(const float* __restrict__ lastR,
                                               const float* __restrict__ lastI,
                                               const float* __restrict__ Mm,
                                               const float* __restrict__ npart,
                                               float* __restrict__ carR,
                                               float* __restrict__ carI) {
  const int c = blockIdx.x & 31, b = blockIdx.x >> 5;
  const int j = threadIdx.x;
  const int oidx = (c * 8 + b) * 256 + j;
  if (c == 0) {  // uniform over block: no barrier divergence
    carR[oidx] = 0.f;
    carI[oidx] = 0.f;
    return;
  }
  __shared__ float lr[256], li[256];
  const int iidx = ((c - 1) * 8 + b) * 256;
  lr[j] = lastR[iidx + j];
  li[j] = lastI[iidx + j];
  __syncthreads();
  float ar = 0.f, ai = 0.f;
  for (int kk = 0; kk < 256; ++kk) {
    float m = Mm[(size_t)kk * 256 + j];
    ar = fmaf(lr[kk], m, ar);
    ai = fmaf(li[kk], m, ai);
  }
  const float s = norm_scale(npart);
  carR[oidx] = lr[j] + s * ar;
  carI[oidx] = li[j] + s * ai;
}

// ---------------- fixup: rez[c,b,t,k] += Re(lam^{t+1} * carry), t<64 --------
// Closed form per t (no serial chain): lam^{t+1} = mag^{t+1} e^{i(t+1)om}.
// mag <= 0.545 => lam^{t+1}*carry < 1e-17 beyond t=64; lam^128 ~ 2e-34 (drop).
// Grid: 31 chunks x 8 batch x 8 t-groups = 1984 blocks, 8 t per thread.
__global__ __launch_bounds__(256) void k_fixup(unsigned short* __restrict__ rez,
                                               const float* __restrict__ carR,
                                               const float* __restrict__ carI,
                                               const float* __restrict__ alpha_raw,
                                               const float* __restrict__ omega) {
  const int tg = blockIdx.x & 7;
  const int cb = blockIdx.x >> 3;           // 0..247
  const int b = cb & 7, c = (cb >> 3) + 1;  // c in [1,32)
  const int k = threadIdx.x;
  const float a = alpha_raw[k];
  const float sig = 1.f / (1.f + expf(-a));
  const float mag = 0.1f + sig * (0.99f - 0.1f);
  const float om = omega[k] * 0.1f;
  const float l2m = log2f(mag);

  const float cr = carR[(c * 8 + b) * 256 + k];
  const float ci = carI[(c * 8 + b) * 256 + k];
  unsigned short* rp =
      rez + ((size_t)b * 4096 + (size_t)c * 128 + tg * 8) * 256 + k;
  #pragma unroll
  for (int tt = 0; tt < 8; ++tt) {
    const float tp1 = (float)(tg * 8 + tt + 1);
    const float p = exp2f(tp1 * l2m);           // mag^(t+1)
    const float ang = tp1 * om;
    const float hr = p * (cosf(ang) * cr - sinf(ang) * ci);
    rp[(size_t)tt * 256] = f2bf(bf2f(rp[(size_t)tt * 256]) + hr);
  }
}

// ---------------------------------------------------------------------------
extern "C" void kernel_launch(void* const* d_in, const int* in_sizes, int n_in,
                              void* d_out, int out_size, void* d_ws,
                              size_t ws_size, hipStream_t stream) {
  const float* x         = (const float*)d_in[0];  // (8,4096,1024)
  const float* alpha_raw = (const float*)d_in[1];  // (256,)
  const float* omega     = (const float*)d_in[2];  // (256,)
  const float* W_in      = (const float*)d_in[3];  // (256,1024)
  const float* W_out     = (const float*)d_in[4];  // (1024,256)
  const float* Mm        = (const float*)d_in[5];  // (256,256)
  float* out = (float*)d_out;                      // (8,4096,1024) fp32

  char* ws = (char*)d_ws;
  unsigned short* rez   = (unsigned short*)(ws);                // 16,777,216 B
  float*          lastR = (float*)(ws + 16777216);              //    262,144 B
  float*          lastI = (float*)(ws + 16777216 + 262144);
  float*          carR  = (float*)(ws + 16777216 + 2 * 262144);
  float*          carI  = (float*)(ws + 16777216 + 3 * 262144);
  unsigned short* WcT   = (unsigned short*)(ws + 16777216 + 4 * 262144); // 524,288 B
  float*          npart = (float*)(ws + 16777216 + 4 * 262144 + 524288); // 256 B
  // W_in bf16 copy parked in d_out (free scratch until GEMM2 overwrites it)
  unsigned short* WinT  = (unsigned short*)d_out;               //    524,288 B

  k_setup<<<320, 256, 0, stream>>>(Mm, npart, W_in, WinT);
  k_wcomb<<<128, 256, 0, stream>>>(W_out, Mm, npart, WcT);
  k_gemm1<<<512, 256, 0, stream>>>(x, WinT, rez, lastR, lastI,
                                   alpha_raw, omega);
  k_carry<<<256, 256, 0, stream>>>(lastR, lastI, Mm, npart, carR, carI);
  k_fixup<<<1984, 256, 0, stream>>>(rez, carR, carI, alpha_raw, omega);
  k_gemm2<<<dim3(256, 8), 256, 0, stream>>>(rez, WcT, out);
}